// Round 3
// baseline (83.182 us; speedup 1.0000x reference)
//
#include <hip/hip_runtime.h>

// Problem constants (from reference)
#define NB 4
#define S_OUT 32                                  // 128 / 4 (two 2x pools fused)
#define NC 64
#define OUT_CELLS (NB * S_OUT * S_OUT * S_OUT)    // 131072
#define OUT_ELEMS (OUT_CELLS * NC)                // 8388608 floats
#define CAP 32                                    // slots per cell (lambda=3.8)
#define OVF_CAP 16384

// ---------- gather path ----------

__global__ void fill_kernel(const int4* __restrict__ coors,
                            int* __restrict__ cnt,
                            int* __restrict__ list,
                            int* __restrict__ ovf_cnt,
                            int* __restrict__ ovf,
                            int n_pts) {
    int p = blockIdx.x * blockDim.x + threadIdx.x;
    if (p >= n_pts) return;
    int4 co = coors[p];
    int cell = ((co.x * S_OUT + (co.y >> 2)) * S_OUT + (co.z >> 2)) * S_OUT + (co.w >> 2);
    int slot = atomicAdd(&cnt[cell], 1);
    if (slot < CAP) {
        list[cell * CAP + slot] = p;
    } else {
        int o = atomicAdd(ovf_cnt, 1);
        if (o < OVF_CAP) ovf[o] = p;
    }
}

// One 64-lane wave per cell; lane = channel. First 8 point-loads issued
// back-to-back (independent) so their latencies overlap; tail loop is rare
// (P(m>8) ~ 1.3% at lambda=3.8).
__global__ __launch_bounds__(256) void gather_kernel(
        const float* __restrict__ features,
        const int* __restrict__ cnt,
        const int* __restrict__ list,
        float* __restrict__ out) {
    int gid = blockIdx.x * blockDim.x + threadIdx.x;
    int cell = gid >> 6;
    int lane = threadIdx.x & 63;
    if (cell >= OUT_CELLS) return;
    int n = cnt[cell];
    int m = n < CAP ? n : CAP;          // wave-uniform
    int pl = (lane < CAP) ? list[cell * CAP + lane] : 0;
    const float* frow = features + lane;
    float acc = -INFINITY;
    #pragma unroll
    for (int k = 0; k < 8; ++k) {
        int p = __shfl(pl, k);
        size_t off = (k < m) ? (size_t)p * NC : 0;   // invalid -> row 0 (L1 hit)
        float f = frow[off];                          // 8 independent loads
        if (k < m) acc = fmaxf(acc, f);
    }
    if (m > 8) {
        for (int k = 8; k < m; ++k) {
            int p = __shfl(pl, k);
            acc = fmaxf(acc, features[(size_t)p * NC + lane]);
        }
    }
    out[(size_t)cell * NC + lane] = (n > 0) ? acc : 0.0f;
}

__device__ __forceinline__ void atomicMaxFloat(float* addr, float val) {
    unsigned* ua = (unsigned*)addr;
    unsigned old = *ua;
    while (true) {
        float f = __uint_as_float(old);
        if (f >= val) break;
        unsigned assumed = old;
        old = atomicCAS(ua, assumed, __float_as_uint(val));
        if (old == assumed) break;
    }
}

// Folds overflow points (expected: zero) into the finished output.
__global__ void ovf_kernel(const float* __restrict__ features,
                           const int4* __restrict__ coors,
                           const int* __restrict__ ovf_cnt,
                           const int* __restrict__ ovf,
                           float* __restrict__ out) {
    int lane = threadIdx.x & 63;
    int wid = (blockIdx.x * blockDim.x + threadIdx.x) >> 6;
    int nw = (gridDim.x * blockDim.x) >> 6;
    int n = *ovf_cnt;
    if (n > OVF_CAP) n = OVF_CAP;
    for (int i = wid; i < n; i += nw) {
        int p = ovf[i];
        int4 co = coors[p];
        int cell = ((co.x * S_OUT + (co.y >> 2)) * S_OUT + (co.z >> 2)) * S_OUT + (co.w >> 2);
        atomicMaxFloat(&out[(size_t)cell * NC + lane], features[(size_t)p * NC + lane]);
    }
}

// ---------- fallback path (R1's working atomicMax scatter) ----------

__device__ __forceinline__ unsigned flip_f(float f) {
    unsigned u = __float_as_uint(f);
    return (u & 0x80000000u) ? ~u : (u | 0x80000000u);
}
__device__ __forceinline__ float unflip_f(unsigned u) {
    unsigned v = (u & 0x80000000u) ? (u & 0x7FFFFFFFu) : ~u;
    return __uint_as_float(v);
}

__global__ void init_kernel(uint4* __restrict__ out4, int n4) {
    int i = blockIdx.x * blockDim.x + threadIdx.x;
    int stride = gridDim.x * blockDim.x;
    uint4 z = make_uint4(0u, 0u, 0u, 0u);
    for (; i < n4; i += stride) out4[i] = z;
}

__global__ void scatter_kernel(const float* __restrict__ features,
                               const int4* __restrict__ coors,
                               unsigned* __restrict__ acc, int n_pts) {
    int gid = blockIdx.x * blockDim.x + threadIdx.x;
    int p = gid >> 6;
    int c = threadIdx.x & 63;
    if (p >= n_pts) return;
    int4 co = coors[p];
    int cell = ((co.x * S_OUT + (co.y >> 2)) * S_OUT + (co.z >> 2)) * S_OUT + (co.w >> 2);
    atomicMax(acc + (size_t)cell * NC + c, flip_f(features[(size_t)p * NC + c]));
}

__global__ void finalize_kernel(unsigned* __restrict__ acc, int n) {
    int i = blockIdx.x * blockDim.x + threadIdx.x;
    int stride = gridDim.x * blockDim.x;
    for (; i < n; i += stride) {
        unsigned u = acc[i];
        ((float*)acc)[i] = (u == 0u) ? 0.0f : unflip_f(u);
    }
}

extern "C" void kernel_launch(void* const* d_in, const int* in_sizes, int n_in,
                              void* d_out, int out_size, void* d_ws, size_t ws_size,
                              hipStream_t stream) {
    const float* features = (const float*)d_in[0];
    const int4*  coors    = (const int4*)d_in[1];
    int n_pts = in_sizes[0] / NC;   // 500000

    // workspace layout
    const size_t off_cnt  = 0;
    const size_t cnt_b    = (size_t)OUT_CELLS * 4;            // 524288
    const size_t off_ovfc = cnt_b;                             // 4B counter
    const size_t off_ovf  = off_ovfc + 256;
    const size_t off_list = off_ovf + (size_t)OVF_CAP * 4;
    const size_t need     = off_list + (size_t)OUT_CELLS * CAP * 4;

    if (ws_size >= need) {
        char* ws = (char*)d_ws;
        int* cnt     = (int*)(ws + off_cnt);
        int* ovf_cnt = (int*)(ws + off_ovfc);
        int* ovf     = (int*)(ws + off_ovf);
        int* list    = (int*)(ws + off_list);
        float* out   = (float*)d_out;

        // zero counters (cnt region + overflow counter)
        hipMemsetAsync(ws, 0, off_ovfc + 4, stream);

        // build per-cell point lists
        {
            int block = 256;
            int grid = (n_pts + block - 1) / block;
            fill_kernel<<<grid, block, 0, stream>>>(coors, cnt, list, ovf_cnt, ovf, n_pts);
        }
        // gather max per cell (writes every output element; no init needed)
        {
            int block = 256;                       // 4 cells per block
            int grid = (OUT_CELLS * 64) / block;   // 32768
            gather_kernel<<<grid, block, 0, stream>>>(features, cnt, list, out);
        }
        // fold overflow points (expected count: 0)
        ovf_kernel<<<1, 256, 0, stream>>>(features, coors, ovf_cnt, ovf, out);
    } else {
        // fallback: R1 atomic scatter path
        unsigned* acc = (unsigned*)d_out;
        init_kernel<<<2048, 256, 0, stream>>>((uint4*)d_out, OUT_ELEMS / 4);
        int grid = (n_pts * 64 + 255) / 256;
        scatter_kernel<<<grid, 256, 0, stream>>>(features, coors, acc, n_pts);
        finalize_kernel<<<2048, 256, 0, stream>>>(acc, OUT_ELEMS);
    }
}

// Round 4
// 64.626 us; speedup vs baseline: 1.2871x; 1.2871x over previous
//
#include <hip/hip_runtime.h>

// Problem constants (from reference)
#define NB 4
#define S_OUT 32                                  // 128 / 4 (two 2x pools fused)
#define NC 64
#define OUT_CELLS (NB * S_OUT * S_OUT * S_OUT)    // 131072
#define OUT_ELEMS (OUT_CELLS * NC)                // 8388608 floats
#define CAP 16                                    // slots per cell (lambda=3.8, P(n>16)=7e-7)
#define OVF_CAP 65536

// ---------- gather path ----------

__global__ void fill_kernel(const int4* __restrict__ coors,
                            int* __restrict__ cnt,
                            int* __restrict__ list,
                            int* __restrict__ ovf_cnt,
                            int* __restrict__ ovf,
                            int n_pts) {
    int p = blockIdx.x * blockDim.x + threadIdx.x;
    if (p >= n_pts) return;
    int4 co = coors[p];
    int cell = ((co.x * S_OUT + (co.y >> 2)) * S_OUT + (co.z >> 2)) * S_OUT + (co.w >> 2);
    int slot = atomicAdd(&cnt[cell], 1);
    if (slot < CAP) {
        list[cell * CAP + slot] = p;
    } else {
        int o = atomicAdd(ovf_cnt, 1);
        if (o < OVF_CAP) ovf[o] = p;
    }
}

// 4 cells per wave; 16-lane group q = lane>>4 owns cell cell0+q; each lane
// holds a float4 channel-quad (cl = (lane&15)*4). No cross-lane reduction.
// list layout [cell][CAP=16] means the wave's 64 lanes load exactly the 4
// cells' 64 slots contiguously: pl = list[cell0*16 + lane]; slot s of group q
// lives in lane (lane&48)+s (source lanes are the group's own -> shfl safe
// under divergence). Output store: out[cell0*64 + lane*4 ..+3] -> 1KB/wave.
__global__ __launch_bounds__(256) void gather_kernel(
        const float* __restrict__ features,
        const int* __restrict__ cnt,
        const int* __restrict__ list,
        float* __restrict__ out) {
    int wid  = (blockIdx.x * blockDim.x + threadIdx.x) >> 6;
    int lane = threadIdx.x & 63;
    int cell0 = wid << 2;
    if (cell0 >= OUT_CELLS) return;

    int n = cnt[cell0 + (lane >> 4)];          // uniform within each 16-lane group
    int m = n < CAP ? n : CAP;
    int pl = list[(size_t)cell0 * CAP + lane]; // coalesced 256B: 4 cells x 16 slots
    int cl = (lane & 15) << 2;
    int sbase = lane & 48;                     // group's slot base lane

    float4 acc = make_float4(-INFINITY, -INFINITY, -INFINITY, -INFINITY);

    // First 8 slots unrolled: 8 independent dwordx4 row-loads per group.
    #pragma unroll
    for (int s = 0; s < 8; ++s) {
        int p = __shfl(pl, sbase + s);
        bool v = s < m;
        int ps = v ? p : 0;                    // invalid -> row 0 (L1-hot dummy)
        const float4 f = *(const float4*)(features + (size_t)ps * NC + cl);
        if (v) {
            acc.x = fmaxf(acc.x, f.x); acc.y = fmaxf(acc.y, f.y);
            acc.z = fmaxf(acc.z, f.z); acc.w = fmaxf(acc.w, f.w);
        }
    }
    // Rare tail (P(n>8) ~ 1.3% per cell)
    if (m > 8) {
        for (int s = 8; s < m; ++s) {
            int p = __shfl(pl, sbase + s);
            const float4 f = *(const float4*)(features + (size_t)p * NC + cl);
            acc.x = fmaxf(acc.x, f.x); acc.y = fmaxf(acc.y, f.y);
            acc.z = fmaxf(acc.z, f.z); acc.w = fmaxf(acc.w, f.w);
        }
    }
    if (n == 0) acc = make_float4(0.f, 0.f, 0.f, 0.f);
    *(float4*)(out + (size_t)cell0 * NC + (size_t)lane * 4) = acc;
}

__device__ __forceinline__ void atomicMaxFloat(float* addr, float val) {
    unsigned* ua = (unsigned*)addr;
    unsigned old = *ua;
    while (true) {
        float f = __uint_as_float(old);
        if (f >= val) break;
        unsigned assumed = old;
        old = atomicCAS(ua, assumed, __float_as_uint(val));
        if (old == assumed) break;
    }
}

// Folds overflow points (expected: ~0 per call) into the finished output.
__global__ void ovf_kernel(const float* __restrict__ features,
                           const int4* __restrict__ coors,
                           const int* __restrict__ ovf_cnt,
                           const int* __restrict__ ovf,
                           float* __restrict__ out) {
    int lane = threadIdx.x & 63;
    int wid = (blockIdx.x * blockDim.x + threadIdx.x) >> 6;
    int nw = (gridDim.x * blockDim.x) >> 6;
    int n = *ovf_cnt;
    if (n > OVF_CAP) n = OVF_CAP;
    for (int i = wid; i < n; i += nw) {
        int p = ovf[i];
        int4 co = coors[p];
        int cell = ((co.x * S_OUT + (co.y >> 2)) * S_OUT + (co.z >> 2)) * S_OUT + (co.w >> 2);
        atomicMaxFloat(&out[(size_t)cell * NC + lane], features[(size_t)p * NC + lane]);
    }
}

// ---------- fallback path (R1's working atomicMax scatter) ----------

__device__ __forceinline__ unsigned flip_f(float f) {
    unsigned u = __float_as_uint(f);
    return (u & 0x80000000u) ? ~u : (u | 0x80000000u);
}
__device__ __forceinline__ float unflip_f(unsigned u) {
    unsigned v = (u & 0x80000000u) ? (u & 0x7FFFFFFFu) : ~u;
    return __uint_as_float(v);
}

__global__ void init_kernel(uint4* __restrict__ out4, int n4) {
    int i = blockIdx.x * blockDim.x + threadIdx.x;
    int stride = gridDim.x * blockDim.x;
    uint4 z = make_uint4(0u, 0u, 0u, 0u);
    for (; i < n4; i += stride) out4[i] = z;
}

__global__ void scatter_kernel(const float* __restrict__ features,
                               const int4* __restrict__ coors,
                               unsigned* __restrict__ acc, int n_pts) {
    int gid = blockIdx.x * blockDim.x + threadIdx.x;
    int p = gid >> 6;
    int c = threadIdx.x & 63;
    if (p >= n_pts) return;
    int4 co = coors[p];
    int cell = ((co.x * S_OUT + (co.y >> 2)) * S_OUT + (co.z >> 2)) * S_OUT + (co.w >> 2);
    atomicMax(acc + (size_t)cell * NC + c, flip_f(features[(size_t)p * NC + c]));
}

__global__ void finalize_kernel(unsigned* __restrict__ acc, int n) {
    int i = blockIdx.x * blockDim.x + threadIdx.x;
    int stride = gridDim.x * blockDim.x;
    for (; i < n; i += stride) {
        unsigned u = acc[i];
        ((float*)acc)[i] = (u == 0u) ? 0.0f : unflip_f(u);
    }
}

extern "C" void kernel_launch(void* const* d_in, const int* in_sizes, int n_in,
                              void* d_out, int out_size, void* d_ws, size_t ws_size,
                              hipStream_t stream) {
    const float* features = (const float*)d_in[0];
    const int4*  coors    = (const int4*)d_in[1];
    int n_pts = in_sizes[0] / NC;   // 500000

    // workspace layout
    const size_t off_cnt  = 0;
    const size_t cnt_b    = (size_t)OUT_CELLS * 4;             // 524288
    const size_t off_ovfc = cnt_b;                             // 4B counter
    const size_t off_ovf  = off_ovfc + 256;
    const size_t off_list = off_ovf + (size_t)OVF_CAP * 4;
    const size_t need     = off_list + (size_t)OUT_CELLS * CAP * 4;   // ~9 MB

    if (ws_size >= need) {
        char* ws = (char*)d_ws;
        int* cnt     = (int*)(ws + off_cnt);
        int* ovf_cnt = (int*)(ws + off_ovfc);
        int* ovf     = (int*)(ws + off_ovf);
        int* list    = (int*)(ws + off_list);
        float* out   = (float*)d_out;

        // zero counters (cnt region + overflow counter)
        hipMemsetAsync(ws, 0, off_ovfc + 4, stream);

        // build per-cell point lists
        {
            int block = 256;
            int grid = (n_pts + block - 1) / block;
            fill_kernel<<<grid, block, 0, stream>>>(coors, cnt, list, ovf_cnt, ovf, n_pts);
        }
        // gather max: 4 cells per wave
        {
            int block = 256;                            // 4 waves = 16 cells/block
            int grid = (OUT_CELLS / 4 * 64) / block;    // 8192
            gather_kernel<<<grid, block, 0, stream>>>(features, cnt, list, out);
        }
        // fold overflow points (expected count: ~0)
        ovf_kernel<<<16, 256, 0, stream>>>(features, coors, ovf_cnt, ovf, out);
    } else {
        // fallback: R1 atomic scatter path
        unsigned* acc = (unsigned*)d_out;
        init_kernel<<<2048, 256, 0, stream>>>((uint4*)d_out, OUT_ELEMS / 4);
        int grid = (n_pts * 64 + 255) / 256;
        scatter_kernel<<<grid, 256, 0, stream>>>(features, coors, acc, n_pts);
        finalize_kernel<<<2048, 256, 0, stream>>>(acc, OUT_ELEMS);
    }
}